// Round 8
// baseline (631.929 us; speedup 1.0000x reference)
//
#include <hip/hip_runtime.h>
#include <math.h>

#define B_ 4
#define T_ 2048
#define D_ 1024
#define H_ 16
#define HD_ 64
#define BT_ (B_ * T_)

typedef __attribute__((ext_vector_type(8))) short bf16x8;
typedef __attribute__((ext_vector_type(8))) _Float16 f16x8;
typedef __attribute__((ext_vector_type(4))) float f32x4;
typedef __attribute__((ext_vector_type(4))) unsigned int u32x4;
typedef unsigned short u16;
typedef unsigned int u32;

// ---- bf16 helpers (RNE) ---------------------------------------------------
__device__ __forceinline__ u16 f2bf(float f) {
  u32 u = __float_as_uint(f);
  u32 r = (u + 0x7FFFu + ((u >> 16) & 1u)) >> 16;
  return (u16)r;
}
__device__ __forceinline__ float bf2f(u16 b) {
  return __uint_as_float(((u32)b) << 16);
}
// ---- fp16 helpers ---------------------------------------------------------
__device__ __forceinline__ u16 f2h(float f) {
  _Float16 h = (_Float16)f;
  return __builtin_bit_cast(u16, h);
}
__device__ __forceinline__ float h2f(u16 b) {
  return (float)__builtin_bit_cast(_Float16, b);
}
// pack 2 f32 -> 2 bf16 in one instruction (T12)
__device__ __forceinline__ u32 cvtpk(float lo, float hi) {
  u32 r;
  asm("v_cvt_pk_bf16_f32 %0, %1, %2" : "=v"(r) : "v"(lo), "v"(hi));
  return r;
}
// async global->LDS, 16B per lane; dest = wave-uniform base + lane*16
__device__ __forceinline__ void gload16(const u16* g, u16* l) {
  __builtin_amdgcn_global_load_lds(
      (const __attribute__((address_space(1))) unsigned int*)g,
      (__attribute__((address_space(3))) unsigned int*)l, 16, 0, 0);
}

// ---------------------------------------------------------------------------
// convert_f16: fp32 -> fp16 (single), flat.  n4 = count/4.
// ---------------------------------------------------------------------------
__global__ __launch_bounds__(256) void convert_f16(
    const float* __restrict__ src, u16* __restrict__ dst, int n4) {
  int i = blockIdx.x * 256 + threadIdx.x;
  const int stride = gridDim.x * 256;
  for (; i < n4; i += stride) {
    float4 v = ((const float4*)src)[i];
    ((ushort4*)dst)[i] = make_ushort4(f2h(v.x), f2h(v.y), f2h(v.z), f2h(v.w));
  }
}

// ---------------------------------------------------------------------------
// convert_wt: Wq/Wk/Wv [h][d][kk] fp32 -> wtf [z][h][kk][d] fp16 (transposed)
// ---------------------------------------------------------------------------
__global__ __launch_bounds__(256) void convert_wt(
    const float* __restrict__ Wq, const float* __restrict__ Wk,
    const float* __restrict__ Wv, u16* __restrict__ wtf) {
  const int d0 = blockIdx.x * 64;
  const int h = blockIdx.y;
  const int z = blockIdx.z;
  const float* W = (z == 0 ? Wq : (z == 1 ? Wk : Wv)) + (size_t)h * D_ * HD_;
  __shared__ float Tl[64][65];
  const int tid = threadIdx.x;
  const int r = tid >> 2;
  const int c0 = (tid & 3) * 16;
#pragma unroll
  for (int j = 0; j < 16; j += 4) {
    float4 v = *(const float4*)(W + (size_t)(d0 + r) * HD_ + c0 + j);
    Tl[c0 + j + 0][r] = v.x; Tl[c0 + j + 1][r] = v.y;
    Tl[c0 + j + 2][r] = v.z; Tl[c0 + j + 3][r] = v.w;
  }
  __syncthreads();
  u16* oh = wtf + (((size_t)z * H_ + h) * HD_ + r) * D_ + d0 + c0;
#pragma unroll
  for (int j = 0; j < 16; j += 4) {
    *(ushort4*)(oh + j) =
        make_ushort4(f2h(Tl[r][c0 + j]), f2h(Tl[r][c0 + j + 1]),
                     f2h(Tl[r][c0 + j + 2]), f2h(Tl[r][c0 + j + 3]));
  }
}

// ---------------------------------------------------------------------------
// qkv_mfma: single-pass fp16 GEMM, z-fused.  grid (BT/128, H), 256 threads.
// 128x64 M-tile; X staged once, 3 W tiles resident.  LDS = 40 KB.
// Outputs bf16: Q scaled by (1/8)*log2(e); K natural; V transposed.
// ---------------------------------------------------------------------------
__global__ __launch_bounds__(256, 2) void qkv_mfma(
    const u16* __restrict__ xf, const u16* __restrict__ wtf,
    u16* __restrict__ Qb, u16* __restrict__ Kb, u16* __restrict__ Vtb) {
  const int m0 = blockIdx.x * 128;
  const int h = blockIdx.y;
  __shared__ __align__(16) u16 Xs[128 * 64];
  __shared__ __align__(16) u16 Ws[3 * 64 * 64];
  const int tid = threadIdx.x;
  const int lane = tid & 63, wave = tid >> 6;
  const int q = lane & 15, g = lane >> 4;

  f32x4 acc[3][2][4];
#pragma unroll
  for (int z = 0; z < 3; ++z)
#pragma unroll
    for (int mt = 0; mt < 2; ++mt)
#pragma unroll
      for (int nt = 0; nt < 4; ++nt)
#pragma unroll
        for (int r = 0; r < 4; ++r) acc[z][mt][nt][r] = 0.f;

  for (int k0 = 0; k0 < D_; k0 += 64) {
#pragma unroll
    for (int i = 0; i < 4; ++i) {
      const int l = wave * 4 + i;
      const int chunk = l * 64 + lane;
      const int row = chunk >> 3, sb = chunk & 7;
      const int so = (sb ^ (row & 7)) * 8;
      gload16(xf + (size_t)(m0 + row) * D_ + k0 + so, &Xs[l * 512]);
    }
#pragma unroll
    for (int z = 0; z < 3; ++z)
#pragma unroll
      for (int i = 0; i < 2; ++i) {
        const int l = wave * 2 + i;
        const int chunk = l * 64 + lane;
        const int row = chunk >> 3, sb = chunk & 7;
        const int so = (sb ^ (row & 7)) * 8;
        gload16(wtf + (((size_t)z * H_ + h) * HD_ + row) * D_ + k0 + so,
                &Ws[z * 4096 + l * 512]);
      }
    __syncthreads();
#pragma unroll
    for (int ks = 0; ks < 2; ++ks) {
      f16x8 ax[2];
#pragma unroll
      for (int mt = 0; mt < 2; ++mt) {
        const int arow = wave * 32 + mt * 16 + q;
        const int ab = arow * 128 + (((g + ks * 4) ^ (arow & 7)) * 16);
        ax[mt] = *(const f16x8*)((const char*)Xs + ab);
      }
#pragma unroll
      for (int z = 0; z < 3; ++z)
#pragma unroll
        for (int nt = 0; nt < 4; ++nt) {
          const int brow = nt * 16 + q;
          const int bb =
              z * 8192 + brow * 128 + (((g + ks * 4) ^ (brow & 7)) * 16);
          f16x8 bw = *(const f16x8*)((const char*)Ws + bb);
#pragma unroll
          for (int mt = 0; mt < 2; ++mt)
            acc[z][mt][nt] = __builtin_amdgcn_mfma_f32_16x16x32_f16(
                ax[mt], bw, acc[z][mt][nt], 0, 0, 0);
        }
    }
    __syncthreads();
  }

  const int b = m0 / T_;
  const int trow0 = m0 % T_;
  const float QSC = 0.125f * 1.44269504f;  // fold log2(e) into Q
  u16* Qd = Qb + (size_t)(b * H_ + h) * T_ * HD_;
  u16* Kd = Kb + (size_t)(b * H_ + h) * T_ * HD_;
  u16* Vd = Vtb + (size_t)(b * H_ + h) * HD_ * T_;
#pragma unroll
  for (int mt = 0; mt < 2; ++mt) {
    const int t_base = trow0 + wave * 32 + mt * 16 + g * 4;
#pragma unroll
    for (int nt = 0; nt < 4; ++nt) {
      const int d = nt * 16 + q;
#pragma unroll
      for (int r = 0; r < 4; ++r) {
        Qd[(size_t)(t_base + r) * HD_ + d] = f2bf(acc[0][mt][nt][r] * QSC);
        Kd[(size_t)(t_base + r) * HD_ + d] = f2bf(acc[1][mt][nt][r]);
      }
      ushort4 v = make_ushort4(f2bf(acc[2][mt][nt][0]), f2bf(acc[2][mt][nt][1]),
                               f2bf(acc[2][mt][nt][2]), f2bf(acc[2][mt][nt][3]));
      *(ushort4*)(Vd + (size_t)d * T_ + t_base) = v;
    }
  }
}

// ---------------------------------------------------------------------------
// attn_mfma: LDS-FREE flash attention.  K/V fragments loaded directly from
// global (L1/L2-resident: fragment addresses are wave-invariant within a
// block; q0-neighbor blocks share via L2).  No barriers, no LDS, waves fully
// independent.  Swapped QK^T, exp2 softmax, cvt_pk, defer-max, register
// ones-vector PV denominator.
// ---------------------------------------------------------------------------
__global__ __launch_bounds__(256) void attn_mfma(
    const u16* __restrict__ Qb, const u16* __restrict__ Kb,
    const u16* __restrict__ Vtb, u16* __restrict__ ch, u16* __restrict__ cl) {
  const int q0 = blockIdx.x * 64;
  const int h = blockIdx.y;
  const int b = blockIdx.z;
  const int tid = threadIdx.x;
  const int lane = tid & 63, wave = tid >> 6;
  const int q = lane & 15, g = lane >> 4;

  const u16* Qg = Qb + ((size_t)(b * H_ + h) * T_ + q0 + wave * 16 + q) * HD_;
  // per-lane fragment bases (wave-invariant):
  // K row = kt + t*16 + q, col d = ks*32 + g*8
  const u16* kbase = Kb + (size_t)(b * H_ + h) * T_ * HD_ + (size_t)q * HD_ + g * 8;
  // V^T row hd = t*16 + q, col key = kt + ks*32 + g*8
  const u16* vbase = Vtb + (size_t)(b * H_ + h) * HD_ * T_ + (size_t)q * T_ + g * 8;

  const bf16x8 qf0 = *(const bf16x8*)(Qg + g * 8);
  const bf16x8 qf1 = *(const bf16x8*)(Qg + 32 + g * 8);

  bf16x8 ones;
#pragma unroll
  for (int j = 0; j < 8; ++j) ones[j] = (short)0x3F80;  // 1.0 bf16

  f32x4 ot[4], ot4;
#pragma unroll
  for (int t = 0; t < 4; ++t)
#pragma unroll
    for (int r = 0; r < 4; ++r) ot[t][r] = 0.f;
#pragma unroll
  for (int r = 0; r < 4; ++r) ot4[r] = 0.f;
  float m_run = -INFINITY;

  for (int kt = 0; kt < T_; kt += 64) {
    // K fragments for this tile (8 x dwordx4, issued upfront)
    bf16x8 kf[2][4];
#pragma unroll
    for (int ks = 0; ks < 2; ++ks)
#pragma unroll
      for (int t = 0; t < 4; ++t)
        kf[ks][t] =
            *(const bf16x8*)(kbase + (size_t)(kt + t * 16) * HD_ + ks * 32);

    // S^T (log2 domain; Q pre-scaled by log2e/8)
    f32x4 st[4];
#pragma unroll
    for (int t = 0; t < 4; ++t)
#pragma unroll
      for (int r = 0; r < 4; ++r) st[t][r] = 0.f;
#pragma unroll
    for (int ks = 0; ks < 2; ++ks) {
      const bf16x8 qf = ks ? qf1 : qf0;
#pragma unroll
      for (int t = 0; t < 4; ++t)
        st[t] =
            __builtin_amdgcn_mfma_f32_16x16x32_bf16(kf[ks][t], qf, st[t], 0, 0, 0);
    }

    // online softmax, exp2 domain, defer-max
    float mx = st[0][0];
#pragma unroll
    for (int t = 0; t < 4; ++t)
#pragma unroll
      for (int r = 0; r < 4; ++r) mx = fmaxf(mx, st[t][r]);
    mx = fmaxf(mx, __shfl_xor(mx, 16));
    mx = fmaxf(mx, __shfl_xor(mx, 32));
    if (!__all(mx <= m_run + 8.f)) {
      const float mnew = fmaxf(m_run, mx);
      const float al = __builtin_amdgcn_exp2f(m_run - mnew);
      m_run = mnew;
#pragma unroll
      for (int t = 0; t < 4; ++t)
#pragma unroll
        for (int r = 0; r < 4; ++r) ot[t][r] *= al;
#pragma unroll
      for (int r = 0; r < 4; ++r) ot4[r] *= al;
    }
    u32 pk[4][2];
#pragma unroll
    for (int t = 0; t < 4; ++t) {
      const float p0 = __builtin_amdgcn_exp2f(st[t][0] - m_run);
      const float p1 = __builtin_amdgcn_exp2f(st[t][1] - m_run);
      const float p2 = __builtin_amdgcn_exp2f(st[t][2] - m_run);
      const float p3 = __builtin_amdgcn_exp2f(st[t][3] - m_run);
      pk[t][0] = cvtpk(p0, p1);
      pk[t][1] = cvtpk(p2, p3);
    }

    // PV: O^T += V^T * P^T  (+ register-ones tile accumulating sum(P))
#pragma unroll
    for (int ks = 0; ks < 2; ++ks) {
      u32 bw[4];
#pragma unroll
      for (int w = 0; w < 4; ++w) {
        const int srcl = ((2 * g + (w >> 1)) & 3) * 16 + q;
        const u32 lo = (u32)__shfl((int)pk[ks * 2][w & 1], srcl);
        const u32 hi2 = (u32)__shfl((int)pk[ks * 2 + 1][w & 1], srcl);
        bw[w] = (g >> 1) ? hi2 : lo;
      }
      u32x4 tmp = {bw[0], bw[1], bw[2], bw[3]};
      bf16x8 pf = __builtin_bit_cast(bf16x8, tmp);
#pragma unroll
      for (int t = 0; t < 4; ++t) {
        bf16x8 vf =
            *(const bf16x8*)(vbase + (size_t)(t * 16) * T_ + kt + ks * 32);
        ot[t] = __builtin_amdgcn_mfma_f32_16x16x32_bf16(vf, pf, ot[t], 0, 0, 0);
      }
      ot4 = __builtin_amdgcn_mfma_f32_16x16x32_bf16(ones, pf, ot4, 0, 0, 0);
    }
  }

  // denominator: every lane's ot4[0] holds l(q) for its own q-col
  const float lsum = ot4[0];
  const float inv = 1.f / lsum;
  const size_t rowbase = (size_t)(b * T_ + q0 + wave * 16 + q) * D_ + h * HD_;
#pragma unroll
  for (int t = 0; t < 4; ++t) {
    float v0 = ot[t][0] * inv, v1 = ot[t][1] * inv;
    float v2 = ot[t][2] * inv, v3 = ot[t][3] * inv;
    ushort4 vh = make_ushort4(f2h(v0), f2h(v1), f2h(v2), f2h(v3));
    ushort4 vl =
        make_ushort4(f2h(v0 - h2f(vh.x)), f2h(v1 - h2f(vh.y)),
                     f2h(v2 - h2f(vh.z)), f2h(v3 - h2f(vh.w)));
    *(ushort4*)(ch + rowbase + t * 16 + g * 4) = vh;
    *(ushort4*)(cl + rowbase + t * 16 + g * 4) = vl;
  }
}

// ---------------------------------------------------------------------------
// oproj_mfma: 2-term fp16 (c_hi*W + c_lo*W), 128x128 tile.  grid (64, 8).
// ---------------------------------------------------------------------------
__global__ __launch_bounds__(256, 2) void oproj_mfma(
    const u16* __restrict__ ch_g, const u16* __restrict__ cl_g,
    const u16* __restrict__ wo_g, float* __restrict__ out) {
  const int m0 = blockIdx.x * 128;
  const int n0 = blockIdx.y * 128;
  __shared__ __align__(16) u16 Ah[128 * 64];
  __shared__ __align__(16) u16 Al[128 * 64];
  __shared__ __align__(16) u16 Bs[128 * 64];
  const int tid = threadIdx.x;
  const int lane = tid & 63, wave = tid >> 6;
  const int q = lane & 15, g = lane >> 4;

  f32x4 acc[2][8];
#pragma unroll
  for (int mt = 0; mt < 2; ++mt)
#pragma unroll
    for (int nt = 0; nt < 8; ++nt)
#pragma unroll
      for (int r = 0; r < 4; ++r) acc[mt][nt][r] = 0.f;

  for (int k0 = 0; k0 < D_; k0 += 64) {
#pragma unroll
    for (int i = 0; i < 4; ++i) {
      const int l = wave * 4 + i;
      const int chunk = l * 64 + lane;
      const int row = chunk >> 3, sb = chunk & 7;
      const int so = (sb ^ (row & 7)) * 8;
      const size_t ga = (size_t)(m0 + row) * D_ + k0 + so;
      const size_t gb = (size_t)(n0 + row) * D_ + k0 + so;
      gload16(ch_g + ga, &Ah[l * 512]);
      gload16(cl_g + ga, &Al[l * 512]);
      gload16(wo_g + gb, &Bs[l * 512]);
    }
    __syncthreads();
#pragma unroll
    for (int ks = 0; ks < 2; ++ks) {
      f16x8 axh[2], axl[2];
#pragma unroll
      for (int mt = 0; mt < 2; ++mt) {
        const int arow = wave * 32 + mt * 16 + q;
        const int ab = arow * 128 + (((g + ks * 4) ^ (arow & 7)) * 16);
        axh[mt] = *(const f16x8*)((const char*)Ah + ab);
        axl[mt] = *(const f16x8*)((const char*)Al + ab);
      }
#pragma unroll
      for (int nt = 0; nt < 8; ++nt) {
        const int brow = nt * 16 + q;
        const int bb = brow * 128 + (((g + ks * 4) ^ (brow & 7)) * 16);
        f16x8 bw = *(const f16x8*)((const char*)Bs + bb);
#pragma unroll
        for (int mt = 0; mt < 2; ++mt) {
          acc[mt][nt] = __builtin_amdgcn_mfma_f32_16x16x32_f16(
              axh[mt], bw, acc[mt][nt], 0, 0, 0);
          acc[mt][nt] = __builtin_amdgcn_mfma_f32_16x16x32_f16(
              axl[mt], bw, acc[mt][nt], 0, 0, 0);
        }
      }
    }
    __syncthreads();
  }

#pragma unroll
  for (int mt = 0; mt < 2; ++mt) {
    const int mrow = m0 + wave * 32 + mt * 16 + g * 4;
#pragma unroll
    for (int nt = 0; nt < 8; ++nt)
#pragma unroll
      for (int r = 0; r < 4; ++r)
        out[(size_t)(mrow + r) * D_ + n0 + nt * 16 + q] = acc[mt][nt][r];
  }
}

// ---------------------------------------------------------------------------
extern "C" void kernel_launch(void* const* d_in, const int* in_sizes, int n_in,
                              void* d_out, int out_size, void* d_ws,
                              size_t ws_size, hipStream_t stream) {
  const float* x = (const float*)d_in[0];
  const float* Wq = (const float*)d_in[1];
  const float* Wk = (const float*)d_in[2];
  const float* Wv = (const float*)d_in[3];
  const float* Wo = (const float*)d_in[4];
  float* out = (float*)d_out;

  u16* ws16 = (u16*)d_ws;
  u16* xf   = ws16;                 //  8,388,608 (fp16 x)
  u16* wtf  = ws16 + 8388608;       //  3,145,728 (fp16 W^T, z-stacked)
  u16* wof  = ws16 + 11534336;      //  1,048,576 (fp16 Wo)
  u16* Qb   = ws16 + 12582912;      //  8,388,608 (bf16)
  u16* Kb   = ws16 + 20971520;      //  8,388,608 (bf16)
  u16* Vtb  = ws16 + 29360128;      //  8,388,608 (bf16, transposed)
  u16* c_lo = ws16 + 37748736;      //  8,388,608 (fp16)
  u16* c_hi = xf;                   //  reuse (x consumed before attn)

  convert_f16<<<2048, 256, 0, stream>>>(x, xf, BT_ * D_ / 4);
  convert_f16<<<1024, 256, 0, stream>>>(Wo, wof, D_ * D_ / 4);
  convert_wt<<<dim3(D_ / 64, H_, 3), 256, 0, stream>>>(Wq, Wk, Wv, wtf);
  qkv_mfma<<<dim3(BT_ / 128, H_), 256, 0, stream>>>(xf, wtf, Qb, Kb, Vtb);
  attn_mfma<<<dim3(T_ / 64, H_, B_), 256, 0, stream>>>(Qb, Kb, Vtb, c_hi, c_lo);
  oproj_mfma<<<dim3(BT_ / 128, D_ / 128), 256, 0, stream>>>(c_hi, c_lo, wof,
                                                            out);
}